// Round 15
// baseline (192.040 us; speedup 1.0000x reference)
//
#include <hip/hip_runtime.h>

// LoRA: out = x @ (A@B) * 1.0, computed as (x@A)@B, FUSED + R/W-OVERLAPPED.
// x: [M=16384, K=4096] f32, A: [K, 16] f32, B: [16, N=4096] f32.
//
// Model (fits r1-r14): read delivery ceiling ~3.1 TB/s (6 structures pegged
// 2.6-3.2 regardless of occupancy/ILP/width); write ceiling ~6.9 TB/s; m13
// copy = 3.15 read + 3.15 write CONCURRENT. r9 = 129.7us = serial floor
// (86 read + 39 write). Remaining win: slide writes under the read window.
//
// Block = 512 thr (8 waves), 32 rows as TWO 16-row sub-tiles; grid 512
// (2 blocks/CU, 16 waves/CU = r9's). Per sub-tile: r14's j-split body
// (wave = 4 rows x 8 j, vals[32], proven correct+fast). Sub-tile 0's T goes
// to Ts[0]; during sub-tile 1's 8-chunk K-loop, after each stage barrier,
// waves store 2 rows of sub-tile 0 (rows 2c, 2c+1) -- reg-light float4
// bursts whose stores drain under the following compute phase. Sub-tile 1's
// rows store at the end (r9-style float4 phase 2 on Ts[1]).

constexpr int RANK = 16;
constexpr int K = 4096;
constexpr int N = 4096;
constexpr int M = 4 * 4096;
constexpr int KC = 512;        // K-chunk staged in LDS (512 rows x 64B = 32KB)
constexpr int NCHUNK = K / KC; // 8
constexpr int ROWST = 16;      // rows per sub-tile
constexpr int ROWSB = 32;      // rows per block (2 sub-tiles)

__global__ __launch_bounds__(512) void lora_fused(const float* __restrict__ x,
                                                  const float* __restrict__ A,
                                                  const float* __restrict__ B,
                                                  float* __restrict__ out) {
  const int tid = threadIdx.x;
  const int lane = tid & 63;
  const int w = tid >> 6;      // 0..7
  const int rg = w & 3;        // row group within sub-tile (4 rows)
  const int jg = w >> 2;       // j half (8 of 16 outputs)
  const int rbase = blockIdx.x * ROWSB;
  const int m = (lane >> 2) & 3;

  __shared__ float4 As[KC * 4];           // 32 KB, swizzled A chunk (r2 layout)
  __shared__ float Ts[2][ROWST][RANK];    // 2 KB, the two T sub-tiles

  const float4* __restrict__ A4 = reinterpret_cast<const float4*>(A);
  const float4* __restrict__ B4 = reinterpret_cast<const float4*>(B);
  float4* __restrict__ out4 = reinterpret_cast<float4*>(out);

  for (int half = 0; half < 2; ++half) {
    const int r0 = rbase + half * ROWST + rg * 4;  // this wave's 4 rows

    float vals[32];
#pragma unroll
    for (int i = 0; i < 32; ++i) vals[i] = 0.0f;

    for (int c = 0; c < NCHUNK; ++c) {
      __syncthreads();  // previous chunk's readers done (also: Ts[0] ready)
      // ---- stage chunk c: 2048 float4 slots, 4 per thread (r14 staging) ----
      // slot s of row k stored at p = s ^ ((k>>2)&3)
#pragma unroll
      for (int q = 0; q < 4; ++q) {
        const int n = q * 512 + tid;              // slot index 0..2047
        const int k = n >> 2;                     // local row
        const int s = n & 3;                      // true slot
        const int p = s ^ ((k >> 2) & 3);         // swizzled position
        As[k * 4 + p] = A4[(size_t)c * 2048 + n];
      }
      __syncthreads();

      // ---- R/W overlap: store 2 finished rows of sub-tile 0 per chunk ----
      if (half == 1) {
        const int rr0 = 2 * c, rr1 = 2 * c + 1;
#pragma unroll 1
        for (int cc = 0; cc < 2; ++cc) {
          const int col = w * 512 + cc * 256 + lane * 4;
          float4 acc0, acc1;
          acc0.x = acc0.y = acc0.z = acc0.w = 0.0f;
          acc1.x = acc1.y = acc1.z = acc1.w = 0.0f;
#pragma unroll 4
          for (int j = 0; j < RANK; ++j) {
            const float4 bj = B4[((size_t)j * N + col) >> 2];
            const float t0 = Ts[0][rr0][j];  // lane-uniform LDS broadcast
            const float t1 = Ts[0][rr1][j];
            acc0.x = fmaf(t0, bj.x, acc0.x); acc0.y = fmaf(t0, bj.y, acc0.y);
            acc0.z = fmaf(t0, bj.z, acc0.z); acc0.w = fmaf(t0, bj.w, acc0.w);
            acc1.x = fmaf(t1, bj.x, acc1.x); acc1.y = fmaf(t1, bj.y, acc1.y);
            acc1.z = fmaf(t1, bj.z, acc1.z); acc1.w = fmaf(t1, bj.w, acc1.w);
          }
          out4[((size_t)(rbase + rr0) * N + col) >> 2] = acc0;
          out4[((size_t)(rbase + rr1) * N + col) >> 2] = acc1;
          // stores drain under the compute below (next barrier is far away)
        }
      }

      // ---- compute: 8 k-blocks of 64 (one k per lane), r14 j-split body ----
#pragma unroll
      for (int kbi = 0; kbi < 8; ++kbi) {
        const int kl = kbi * 64 + lane;           // local k in chunk
        const size_t kg = (size_t)c * KC + kl;    // global k

        float xv[4];
#pragma unroll
        for (int r = 0; r < 4; ++r) xv[r] = x[(size_t)(r0 + r) * K + kg];

        float4 a[2];
#pragma unroll
        for (int ss = 0; ss < 2; ++ss)
          a[ss] = As[kl * 4 + ((2 * jg + ss) ^ m)];

#pragma unroll
        for (int r = 0; r < 4; ++r) {
#pragma unroll
          for (int ss = 0; ss < 2; ++ss) {
            vals[r * 8 + ss * 4 + 0] = fmaf(xv[r], a[ss].x, vals[r * 8 + ss * 4 + 0]);
            vals[r * 8 + ss * 4 + 1] = fmaf(xv[r], a[ss].y, vals[r * 8 + ss * 4 + 1]);
            vals[r * 8 + ss * 4 + 2] = fmaf(xv[r], a[ss].z, vals[r * 8 + ss * 4 + 2]);
            vals[r * 8 + ss * 4 + 3] = fmaf(xv[r], a[ss].w, vals[r * 8 + ss * 4 + 3]);
          }
        }
      }
    }

    // 5-fold reduce-scatter over lane bits {32,16,8,4,2} (r14-proven), then
    // butterfly over bit 1: even lane 2e holds element e (row e>>3, jj e&7).
#define FOLD(AH, LB)                                           \
    {                                                          \
      const bool hi = (lane & (LB)) != 0;                      \
      _Pragma("unroll")                                        \
      for (int i = 0; i < (AH); ++i) {                         \
        const float send = hi ? vals[i] : vals[i + (AH)];      \
        const float keep = hi ? vals[i + (AH)] : vals[i];      \
        vals[i] = keep + __shfl_xor(send, (LB), 64);           \
      }                                                        \
    }
    FOLD(16, 32)
    FOLD(8, 16)
    FOLD(4, 8)
    FOLD(2, 4)
    FOLD(1, 2)
#undef FOLD
    vals[0] += __shfl_xor(vals[0], 1, 64);

    if (!(lane & 1)) {
      const int e = lane >> 1;  // 0..31
      Ts[half][rg * 4 + (e >> 3)][jg * 8 + (e & 7)] = vals[0];
    }
    // Ts[half] consumers are separated by the next barrier (chunk loop or
    // the final-phase barrier below).
  }

  __syncthreads();  // Ts[1] complete

  // ---- final: store sub-tile 1's 16 rows (r9-style float4 phase 2) ----
#pragma unroll 1
  for (int cc = 0; cc < 2; ++cc) {
    const int col = w * 512 + cc * 256 + lane * 4;

    float4 b[16];
#pragma unroll
    for (int j = 0; j < RANK; ++j) b[j] = B4[((size_t)j * N + col) >> 2];

#pragma unroll 1
    for (int r = 0; r < ROWST; ++r) {
      const float4* __restrict__ tr4 =
          reinterpret_cast<const float4*>(&Ts[1][r][0]);
      const float4 t0 = tr4[0];
      const float4 t1 = tr4[1];
      const float4 t2 = tr4[2];
      const float4 t3 = tr4[3];
      const float tsv[16] = {t0.x, t0.y, t0.z, t0.w, t1.x, t1.y, t1.z, t1.w,
                             t2.x, t2.y, t2.z, t2.w, t3.x, t3.y, t3.z, t3.w};

      float4 acc;
      acc.x = acc.y = acc.z = acc.w = 0.0f;
#pragma unroll
      for (int j = 0; j < RANK; ++j) {
        acc.x = fmaf(tsv[j], b[j].x, acc.x);
        acc.y = fmaf(tsv[j], b[j].y, acc.y);
        acc.z = fmaf(tsv[j], b[j].z, acc.z);
        acc.w = fmaf(tsv[j], b[j].w, acc.w);
      }
      out4[((size_t)(rbase + ROWST + r) * N + col) >> 2] = acc;
    }
  }
}

extern "C" void kernel_launch(void* const* d_in, const int* in_sizes, int n_in,
                              void* d_out, int out_size, void* d_ws, size_t ws_size,
                              hipStream_t stream) {
  const float* x = (const float*)d_in[0];   // [M, K]
  const float* A = (const float*)d_in[1];   // [K, RANK]
  const float* B = (const float*)d_in[2];   // [RANK, N]
  float* out = (float*)d_out;               // [M, N]
  (void)d_ws; (void)ws_size;

  // 32 rows per block -> 512 blocks of 512 threads (2 blocks/CU).
  lora_fused<<<M / ROWSB, 512, 0, stream>>>(x, A, B, out);
}

// Round 16
// 129.040 us; speedup vs baseline: 1.4882x; 1.4882x over previous
//
#include <hip/hip_runtime.h>

// LoRA: out = x @ (A@B) * 1.0, computed as (x@A)@B, FUSED in one kernel.
// x: [M=16384, K=4096] f32, A: [K, 16] f32, B: [16, N=4096] f32.
//
// == FINAL: r9 verbatim — the measured optimum (129.7 us) over 15 rounds. ==
// Model: ~3.1 TB/s read-delivery ceiling for this streaming pattern (six
// diverse structures pegged 2.6-3.2 TB/s), ~6.9 TB/s write ceiling, no
// productive R/W overlap from within the kernel (r14/r15). Serial floor
// ~125 us; this kernel is within ~4% of it. All 6 attempted refinements
// (async staging, wider loads, ILP prefetch, 2x TLP, launch_bounds hints,
// R/W overlap) regressed or were neutral.
//
// Phase 1 (per block of 16 rows): T-tile = x-rows @ A.
//   - A chunk (32 KB) staged in LDS, slot-XOR swizzled: slot s of row k at
//     p = s ^ ((k>>2)&3) -> conflict-free 8-phase wave64 ds_read_b128.
//   - x read as scalar dwords, lane l owns k = kb*64+l (coalesced 256B/wave).
//   - vals[64] = 4 rows x 16 j per wave; 16 FMAs per load.
//   - Epilogue: recursive-halving reduce-scatter (63 shuffles) -> lane i
//     holds element i of the wave's 4x16 tile -> LDS T-tile handoff.
// Phase 2: out-tile = T-tile @ B. B fragment (16 float4) loaded once per
//   256-col pass; T rows broadcast from LDS (same-addr = free); coalesced
//   float4 stores at the ~6.9 TB/s write ceiling.
constexpr int RANK = 16;
constexpr int K = 4096;
constexpr int N = 4096;
constexpr int M = 4 * 4096;
constexpr int KC = 512;       // K-chunk staged in LDS (512 rows x 64B = 32KB)
constexpr int NCHUNK = K / KC;

__global__ __launch_bounds__(256) void lora_fused(const float* __restrict__ x,
                                                  const float* __restrict__ A,
                                                  const float* __restrict__ B,
                                                  float* __restrict__ out) {
  const int lane = threadIdx.x & 63;
  const int tid = threadIdx.x;
  const int wave = tid >> 6;
  const int rbase = blockIdx.x * 16;
  const int r0 = rbase + wave * 4;  // this wave's 4 rows (phase 1)

  __shared__ float4 As[KC * 4];     // 32 KB, swizzled A chunk (r2 layout)
  __shared__ float Ts[16][RANK];    // 1 KB, block's T-tile

  const float4* __restrict__ A4 = reinterpret_cast<const float4*>(A);

  // ================= Phase 1: T-tile = x @ A =============
  float vals[64];
#pragma unroll
  for (int i = 0; i < 64; ++i) vals[i] = 0.0f;

  for (int c = 0; c < NCHUNK; ++c) {
    __syncthreads();  // previous chunk's readers done
    // ---- stage chunk c: KC*4 = 2048 float4 slots, 8 per thread ----
    // slot s of row k stored at p = s ^ ((k>>2)&3)
#pragma unroll
    for (int q = 0; q < 8; ++q) {
      const int n = q * 256 + tid;              // slot index 0..2047
      const int k = n >> 2;                     // local row
      const int s = n & 3;                      // true slot
      const int p = s ^ ((k >> 2) & 3);         // swizzled position
      As[k * 4 + p] = A4[(size_t)c * 2048 + n];
    }
    __syncthreads();

    // ---- compute: 8 k-blocks of 64 (one k per lane) ----
    const int m = (lane >> 2) & 3;
#pragma unroll
    for (int kbi = 0; kbi < 8; ++kbi) {
      const int kl = kbi * 64 + lane;           // local k in chunk
      const size_t kg = (size_t)c * KC + kl;    // global k

      float xv[4];
#pragma unroll
      for (int r = 0; r < 4; ++r) xv[r] = x[(size_t)(r0 + r) * K + kg];

      float4 a[4];
#pragma unroll
      for (int s = 0; s < 4; ++s) a[s] = As[kl * 4 + (s ^ m)];

#pragma unroll
      for (int r = 0; r < 4; ++r) {
#pragma unroll
        for (int s = 0; s < 4; ++s) {
          vals[r * 16 + 4 * s + 0] = fmaf(xv[r], a[s].x, vals[r * 16 + 4 * s + 0]);
          vals[r * 16 + 4 * s + 1] = fmaf(xv[r], a[s].y, vals[r * 16 + 4 * s + 1]);
          vals[r * 16 + 4 * s + 2] = fmaf(xv[r], a[s].z, vals[r * 16 + 4 * s + 2]);
          vals[r * 16 + 4 * s + 3] = fmaf(xv[r], a[s].w, vals[r * 16 + 4 * s + 3]);
        }
      }
    }
  }

  // Reduce-scatter: lane i ends with element i (r=i>>4, j=i&15).
#define RSTEP(HALF)                                            \
  {                                                            \
    const bool hi = (lane & (HALF)) != 0;                      \
    _Pragma("unroll")                                          \
    for (int i = 0; i < (HALF); ++i) {                         \
      const float send = hi ? vals[i] : vals[i + (HALF)];      \
      const float keep = hi ? vals[i + (HALF)] : vals[i];      \
      vals[i] = keep + __shfl_xor(send, (HALF), 64);           \
    }                                                          \
  }
  RSTEP(32)
  RSTEP(16)
  RSTEP(8)
  RSTEP(4)
  RSTEP(2)
  RSTEP(1)
#undef RSTEP

  // Hand off T-tile via LDS (1 write/lane, conflict-free).
  Ts[wave * 4 + (lane >> 4)][lane & 15] = vals[0];
  __syncthreads();

  // ================= Phase 2: out-tile = T-tile @ B ========
  const float4* __restrict__ B4 = reinterpret_cast<const float4*>(B);
  float4* __restrict__ out4 = reinterpret_cast<float4*>(out);

#pragma unroll 1
  for (int cc = 0; cc < 4; ++cc) {
    const int col = wave * 1024 + cc * 256 + lane * 4;

    float4 b[16];
#pragma unroll
    for (int j = 0; j < RANK; ++j) b[j] = B4[((size_t)j * N + col) >> 2];

#pragma unroll 1
    for (int r = 0; r < 16; ++r) {
      // Broadcast T row r (same addr all lanes -> free LDS broadcast).
      const float4* __restrict__ tr4 =
          reinterpret_cast<const float4*>(&Ts[r][0]);
      const float4 t0 = tr4[0];
      const float4 t1 = tr4[1];
      const float4 t2 = tr4[2];
      const float4 t3 = tr4[3];

      float4 acc;
      acc.x = acc.y = acc.z = acc.w = 0.0f;
      const float tsv[16] = {t0.x, t0.y, t0.z, t0.w, t1.x, t1.y, t1.z, t1.w,
                             t2.x, t2.y, t2.z, t2.w, t3.x, t3.y, t3.z, t3.w};
#pragma unroll
      for (int j = 0; j < RANK; ++j) {
        acc.x = fmaf(tsv[j], b[j].x, acc.x);
        acc.y = fmaf(tsv[j], b[j].y, acc.y);
        acc.z = fmaf(tsv[j], b[j].z, acc.z);
        acc.w = fmaf(tsv[j], b[j].w, acc.w);
      }
      out4[((size_t)(rbase + r) * N + col) >> 2] = acc;
    }
  }
}

extern "C" void kernel_launch(void* const* d_in, const int* in_sizes, int n_in,
                              void* d_out, int out_size, void* d_ws, size_t ws_size,
                              hipStream_t stream) {
  const float* x = (const float*)d_in[0];   // [M, K]
  const float* A = (const float*)d_in[1];   // [K, RANK]
  const float* B = (const float*)d_in[2];   // [RANK, N]
  float* out = (float*)d_out;               // [M, N]
  (void)d_ws; (void)ws_size;

  // One fused kernel: 16 rows per block -> 1024 blocks.
  lora_fused<<<M / 16, 256, 0, stream>>>(x, A, B, out);
}